// Round 5
// baseline (120.896 us; speedup 1.0000x reference)
//
#include <hip/hip_runtime.h>
#include <hip/hip_bf16.h>
#include <cstddef>

typedef __bf16 bf16x8 __attribute__((ext_vector_type(8)));
typedef float  f32x4  __attribute__((ext_vector_type(4)));

#define NB 16
#define NL 512
#define NH 768
#define NROWS (NB*NL)      // 8192
#define NSEQ 128           // seq columns
#define NPAD 192           // padded GEMM N: 128 seq + 24 bias + 40 zero
#define NHEADS 12
#define NBIAS 24           // 2*HEADS
#define DHEAD 64
#define BIGNEG 1000000000000.0f

// workspace byte offsets
#define OFF_PWT   0            // bf16 [192][768]   = 294912 B
#define OFF_B2    294912       // f32 [24] (pad 128)
#define OFF_QRB   295040       // bf16 [16][512][64] = 1 MB  (roped q, [l][d])
#define OFF_KRB   1343616      // bf16 [16][512][64] = 1 MB
#define OFF_BIAS  2392192      // f32 [16][2][12][512] = 786432 B (b0/b1 planes)
// total 3178624 B

__global__ void prep_wt(const float* __restrict__ pW, const float* __restrict__ qW,
                        const float* __restrict__ pb, const float* __restrict__ qb,
                        __bf16* __restrict__ pWT, float* __restrict__ b2) {
  if (blockIdx.x == 576) {
    int c = threadIdx.x;
    if (c < NBIAS) {
      float a = qb[c];
      for (int j = 0; j < NSEQ; ++j) a += pb[j] * qW[j * NBIAS + c];
      b2[c] = a;
    }
    return;
  }
  int idx = blockIdx.x * 256 + threadIdx.x;   // covers NPAD*NH exactly
  int n = idx / NH, k = idx % NH;
  float v = 0.f;
  if (n < NSEQ) {
    v = pW[k * NSEQ + n];
  } else if (n < NSEQ + NBIAS) {
    int c = n - NSEQ;
    float a = 0.f;
    for (int j = 0; j < NSEQ; ++j) a += pW[k * NSEQ + j] * qW[j * NBIAS + c];
    v = a;
  }
  pWT[idx] = (__bf16)v;
}

__launch_bounds__(256)
__global__ void gemm_rope(const float* __restrict__ hidden, const __bf16* __restrict__ pWT,
                          const float* __restrict__ pb, const float* __restrict__ b2,
                          __bf16* __restrict__ qrB, __bf16* __restrict__ krB,
                          float* __restrict__ biasw) {
  int m0 = blockIdx.x * 16;
  int tid = threadIdx.x;
  int wave = tid >> 6, lane = tid & 63;
  int lrow = lane & 15, lk = (lane >> 4) * 8;
  f32x4 acc0 = {0,0,0,0}, acc1 = {0,0,0,0}, acc2 = {0,0,0,0};
  const float*  arow = hidden + (size_t)(m0 + lrow) * NH;
  const __bf16* bp0  = pWT + (size_t)((wave*3+0)*16 + lrow) * NH;
  const __bf16* bp1  = pWT + (size_t)((wave*3+1)*16 + lrow) * NH;
  const __bf16* bp2  = pWT + (size_t)((wave*3+2)*16 + lrow) * NH;
  for (int k0 = 0; k0 < NH; k0 += 32) {
    f32x4 h0 = *(const f32x4*)(arow + k0 + lk);
    f32x4 h1 = *(const f32x4*)(arow + k0 + lk + 4);
    bf16x8 af;
    af[0]=(__bf16)h0[0]; af[1]=(__bf16)h0[1]; af[2]=(__bf16)h0[2]; af[3]=(__bf16)h0[3];
    af[4]=(__bf16)h1[0]; af[5]=(__bf16)h1[1]; af[6]=(__bf16)h1[2]; af[7]=(__bf16)h1[3];
    bf16x8 b0 = *(const bf16x8*)(bp0 + k0 + lk);
    bf16x8 b1 = *(const bf16x8*)(bp1 + k0 + lk);
    bf16x8 b2f = *(const bf16x8*)(bp2 + k0 + lk);
    acc0 = __builtin_amdgcn_mfma_f32_16x16x32_bf16(af, b0, acc0, 0, 0, 0);
    acc1 = __builtin_amdgcn_mfma_f32_16x16x32_bf16(af, b1, acc1, 0, 0, 0);
    acc2 = __builtin_amdgcn_mfma_f32_16x16x32_bf16(af, b2f, acc2, 0, 0, 0);
  }
  int rowoff = (lane >> 4) * 4;
  #pragma unroll
  for (int f = 0; f < 3; ++f) {
    f32x4 a = (f == 0) ? acc0 : (f == 1) ? acc1 : acc2;
    int col = (wave*3 + f) * 16 + lrow;
    bool isseq = (col < NSEQ);
    float addc = isseq ? pb[col] : ((col < NSEQ + NBIAS) ? b2[col - NSEQ] : 0.f);
    #pragma unroll
    for (int r = 0; r < 4; ++r) {
      int rg = m0 + rowoff + r;
      float val = a[r] + addc;
      if (isseq) {
        float pv = __shfl_xor(val, 1, 64);
        int d = col & 63;
        float x2 = (d & 1) ? pv : -pv;
        int p = d >> 1;
        float ang = (float)(rg & (NL - 1)) * __expf((float)p * (-9.210340371976184f / 32.0f));
        float sn = __sinf(ang), cs = __cosf(ang);
        float res = val * cs + x2 * sn;
        int bi = rg >> 9, l = rg & (NL - 1);
        __bf16* dst = (col < DHEAD) ? qrB : krB;
        dst[((size_t)bi * NL + l) * DHEAD + d] = (__bf16)res;
      } else if (col < NSEQ + NBIAS) {
        int c2 = col - NSEQ;
        int h = c2 >> 1, par = c2 & 1;
        int bi = rg >> 9, l = rg & (NL - 1);
        biasw[(((size_t)bi * 2 + par) * NHEADS + h) * NL + l] = val;
      }
    }
  }
}

__launch_bounds__(256)
__global__ void logits_kernel(const __bf16* __restrict__ qr, const __bf16* __restrict__ kr,
                              const float* __restrict__ biasw, const int* __restrict__ amask,
                              float* __restrict__ out) {
  int nx = blockIdx.x, mt = blockIdx.y, bz = blockIdx.z;
  int n0 = nx * 128, m0 = mt * 16;
  int tid = threadIdx.x;
  __shared__ float ls[16][128];
  __shared__ float b1h[NHEADS][128];
  __shared__ float b0h[NHEADS][16];
  __shared__ float padf[128];
  const float* bw = biasw + (size_t)bz * 2 * NHEADS * NL;
  for (int i = tid; i < NHEADS * 128 / 4; i += 256) {
    int h = i >> 5, c = (i & 31) * 4;
    *(f32x4*)&b1h[h][c] = *(const f32x4*)(bw + NHEADS * NL + h * NL + n0 + c);
  }
  if (tid < NHEADS * 16) {
    int h = tid >> 4, r = tid & 15;
    b0h[h][r] = bw[h * NL + m0 + r];
  }
  if (tid < 128) padf[tid] = (float)amask[bz * NL + n0 + tid];

  int wave = tid >> 6, lane = tid & 63;
  int lr = lane & 15, koff = (lane >> 4) * 8;
  const __bf16* qb = qr + ((size_t)(bz * NL + m0 + lr)) * DHEAD + koff;
  bf16x8 a0 = *(const bf16x8*)qb;
  bf16x8 a1 = *(const bf16x8*)(qb + 32);
  int rowb = (lane >> 4) * 4;
  #pragma unroll
  for (int s = 0; s < 2; ++s) {
    int ncol = (wave * 2 + s) * 16;
    const __bf16* kb = kr + ((size_t)(bz * NL + n0 + ncol + lr)) * DHEAD + koff;
    bf16x8 b0f = *(const bf16x8*)kb;
    bf16x8 b1f = *(const bf16x8*)(kb + 32);
    f32x4 acc = {0,0,0,0};
    acc = __builtin_amdgcn_mfma_f32_16x16x32_bf16(a0, b0f, acc, 0, 0, 0);
    acc = __builtin_amdgcn_mfma_f32_16x16x32_bf16(a1, b1f, acc, 0, 0, 0);
    #pragma unroll
    for (int r = 0; r < 4; ++r) ls[rowb + r][ncol + lr] = acc[r] * 0.125f;
  }
  __syncthreads();

  #pragma unroll
  for (int half = 0; half < 2; ++half) {
    int flat = half * 1024 + tid * 4;
    int rr = flat >> 7, c = flat & 127;
    int mg = m0 + rr;
    f32x4 s4 = *(f32x4*)&ls[rr][c];
    f32x4 pv = *(f32x4*)&padf[c];
    f32x4 sm;
    #pragma unroll
    for (int j = 0; j < 4; ++j) {
      float v = s4[j] * pv[j] - (1.f - pv[j]) * BIGNEG;
      if (mg > n0 + c + j) v -= BIGNEG;
      sm[j] = v;
    }
    float* ob = out + ((size_t)(bz * NHEADS) * NL + mg) * NL + n0 + c;
    #pragma unroll
    for (int h = 0; h < NHEADS; ++h) {
      f32x4 b1v = *(f32x4*)&b1h[h][c];
      float b0v = b0h[h][rr];
      f32x4 o;
      #pragma unroll
      for (int j = 0; j < 4; ++j)
        o[j] = sm[j] + (b0v + b1v[j]) * pv[j];
      __builtin_nontemporal_store(o, (f32x4*)(ob + (size_t)h * NL * NL));
    }
  }
}

extern "C" void kernel_launch(void* const* d_in, const int* in_sizes, int n_in,
                              void* d_out, int out_size, void* d_ws, size_t ws_size,
                              hipStream_t stream) {
  const float* hidden = (const float*)d_in[0];
  const int*   amask  = (const int*)d_in[1];
  const float* pW     = (const float*)d_in[2];
  const float* pb     = (const float*)d_in[3];
  const float* qW     = (const float*)d_in[4];
  const float* qb     = (const float*)d_in[5];
  float* out = (float*)d_out;
  char*  ws  = (char*)d_ws;
  __bf16* pWT  = (__bf16*)(ws + OFF_PWT);
  float*  b2   = (float*)(ws + OFF_B2);
  __bf16* qrB  = (__bf16*)(ws + OFF_QRB);
  __bf16* krB  = (__bf16*)(ws + OFF_KRB);
  float*  bias = (float*)(ws + OFF_BIAS);

  prep_wt<<<577, 256, 0, stream>>>(pW, qW, pb, qb, pWT, b2);
  gemm_rope<<<NROWS / 16, 256, 0, stream>>>(hidden, pWT, pb, b2, qrB, krB, bias);
  // Launched TWICE on purpose: deterministic & output-identical (idempotent
  // full overwrite of d_out). dur_us minus round-4's 81.2 us == T_logits,
  // the per-kernel attribution rocprof's fill-flooded top-5 can't give us.
  logits_kernel<<<dim3(4, NL / 16, NB), 256, 0, stream>>>(qrB, krB, bias, amask, out);
  logits_kernel<<<dim3(4, NL / 16, NB), 256, 0, stream>>>(qrB, krB, bias, amask, out);
}

// Round 6
// 101.019 us; speedup vs baseline: 1.1968x; 1.1968x over previous
//
#include <hip/hip_runtime.h>
#include <hip/hip_bf16.h>
#include <cstddef>

typedef __bf16 bf16x8 __attribute__((ext_vector_type(8)));
typedef float  f32x4  __attribute__((ext_vector_type(4)));

#define NB 16
#define NL 512
#define NH 768
#define NROWS (NB*NL)      // 8192
#define NSEQ 128           // seq columns
#define NPAD 192           // padded GEMM N: 128 seq + 24 bias + 40 zero
#define NHEADS 12
#define NBIAS 24           // 2*HEADS
#define DHEAD 64
#define BIGNEG 1000000000000.0f

// workspace byte offsets
#define OFF_PWT   0            // bf16 k-panel [96][192][8] = 294912 B
#define OFF_B2    294912       // f32 [24] (pad 128)
#define OFF_QRB   295040       // bf16 [16][512][64] = 1 MB  (roped q, [l][d])
#define OFF_KRB   1343616      // bf16 [16][512][64] = 1 MB
#define OFF_BIAS  2392192      // f32 [16][2][12][512] = 786432 B (b0/b1 planes)
// total 3178624 B

// pWT k-panel layout: element (n,k) at [(k>>3)*192 + n]*8 + (k&7).
// A B-frag load (16 lanes, consecutive n, same 8k-chunk) is 256 B contiguous.
__global__ void prep_wt(const float* __restrict__ pW, const float* __restrict__ qW,
                        const float* __restrict__ pb, const float* __restrict__ qb,
                        __bf16* __restrict__ pWT, float* __restrict__ b2) {
  if (blockIdx.x == 576) {
    int c = threadIdx.x;
    if (c < NBIAS) {
      float a = qb[c];
      for (int j = 0; j < NSEQ; ++j) a += pb[j] * qW[j * NBIAS + c];
      b2[c] = a;
    }
    return;
  }
  int idx = blockIdx.x * 256 + threadIdx.x;   // covers NPAD*NH exactly
  int n = idx / NH, k = idx % NH;
  float v = 0.f;
  if (n < NSEQ) {
    v = pW[k * NSEQ + n];
  } else if (n < NSEQ + NBIAS) {
    int c = n - NSEQ;
    float a = 0.f;
    for (int j = 0; j < NSEQ; ++j) a += pW[k * NSEQ + j] * qW[j * NBIAS + c];
    v = a;
  }
  pWT[((size_t)(k >> 3) * NPAD + n) * 8 + (k & 7)] = (__bf16)v;
}

__launch_bounds__(256)
__global__ void gemm_rope(const float* __restrict__ hidden, const __bf16* __restrict__ pWT,
                          const float* __restrict__ pb, const float* __restrict__ b2,
                          __bf16* __restrict__ qrB, __bf16* __restrict__ krB,
                          float* __restrict__ biasw) {
  int m0 = blockIdx.x * 16;
  int tid = threadIdx.x;
  int wave = tid >> 6, lane = tid & 63;
  int lrow = lane & 15, lk = (lane >> 4) * 8;
  f32x4 acc0 = {0,0,0,0}, acc1 = {0,0,0,0}, acc2 = {0,0,0,0};
  const float* arow = hidden + (size_t)(m0 + lrow) * NH;
  // k-panel B pointers: base + k0*NPAD walks the panels
  const __bf16* bb0 = pWT + (size_t)(lane >> 4) * NPAD * 8 + ((wave*3+0)*16 + lrow) * 8;
  const __bf16* bb1 = pWT + (size_t)(lane >> 4) * NPAD * 8 + ((wave*3+1)*16 + lrow) * 8;
  const __bf16* bb2 = pWT + (size_t)(lane >> 4) * NPAD * 8 + ((wave*3+2)*16 + lrow) * 8;
  #pragma unroll 2
  for (int k0 = 0; k0 < NH; k0 += 32) {
    f32x4 h0 = *(const f32x4*)(arow + k0 + lk);
    f32x4 h1 = *(const f32x4*)(arow + k0 + lk + 4);
    bf16x8 af;
    af[0]=(__bf16)h0[0]; af[1]=(__bf16)h0[1]; af[2]=(__bf16)h0[2]; af[3]=(__bf16)h0[3];
    af[4]=(__bf16)h1[0]; af[5]=(__bf16)h1[1]; af[6]=(__bf16)h1[2]; af[7]=(__bf16)h1[3];
    bf16x8 b0 = *(const bf16x8*)(bb0 + (size_t)k0 * NPAD);
    bf16x8 b1 = *(const bf16x8*)(bb1 + (size_t)k0 * NPAD);
    bf16x8 b2f = *(const bf16x8*)(bb2 + (size_t)k0 * NPAD);
    acc0 = __builtin_amdgcn_mfma_f32_16x16x32_bf16(af, b0, acc0, 0, 0, 0);
    acc1 = __builtin_amdgcn_mfma_f32_16x16x32_bf16(af, b1, acc1, 0, 0, 0);
    acc2 = __builtin_amdgcn_mfma_f32_16x16x32_bf16(af, b2f, acc2, 0, 0, 0);
  }
  int rowoff = (lane >> 4) * 4;
  #pragma unroll
  for (int f = 0; f < 3; ++f) {
    f32x4 a = (f == 0) ? acc0 : (f == 1) ? acc1 : acc2;
    int col = (wave*3 + f) * 16 + lrow;
    bool isseq = (col < NSEQ);
    float addc = isseq ? pb[col] : ((col < NSEQ + NBIAS) ? b2[col - NSEQ] : 0.f);
    #pragma unroll
    for (int r = 0; r < 4; ++r) {
      int rg = m0 + rowoff + r;
      float val = a[r] + addc;
      if (isseq) {
        float pv = __shfl_xor(val, 1, 64);
        int d = col & 63;
        float x2 = (d & 1) ? pv : -pv;
        int p = d >> 1;
        float ang = (float)(rg & (NL - 1)) * __expf((float)p * (-9.210340371976184f / 32.0f));
        float sn = __sinf(ang), cs = __cosf(ang);
        float res = val * cs + x2 * sn;
        int bi = rg >> 9, l = rg & (NL - 1);
        __bf16* dst = (col < DHEAD) ? qrB : krB;
        dst[((size_t)bi * NL + l) * DHEAD + d] = (__bf16)res;
      } else if (col < NSEQ + NBIAS) {
        int c2 = col - NSEQ;
        int h = c2 >> 1, par = c2 & 1;
        int bi = rg >> 9, l = rg & (NL - 1);
        biasw[(((size_t)bi * 2 + par) * NHEADS + h) * NL + l] = val;
      }
    }
  }
}

__launch_bounds__(256)
__global__ void logits_kernel(const __bf16* __restrict__ qr, const __bf16* __restrict__ kr,
                              const float* __restrict__ biasw, const int* __restrict__ amask,
                              float* __restrict__ out) {
  int nx = blockIdx.x, mt = blockIdx.y, bz = blockIdx.z;
  int n0 = nx * 128, m0 = mt * 16;
  int tid = threadIdx.x;
  __shared__ float ls[16][128];
  __shared__ float b1h[NHEADS][128];
  __shared__ float b0h[NHEADS][16];
  __shared__ float padf[128];
  const float* bw = biasw + (size_t)bz * 2 * NHEADS * NL;
  for (int i = tid; i < NHEADS * 128 / 4; i += 256) {
    int h = i >> 5, c = (i & 31) * 4;
    *(f32x4*)&b1h[h][c] = *(const f32x4*)(bw + NHEADS * NL + h * NL + n0 + c);
  }
  if (tid < NHEADS * 16) {
    int h = tid >> 4, r = tid & 15;
    b0h[h][r] = bw[h * NL + m0 + r];
  }
  if (tid < 128) padf[tid] = (float)amask[bz * NL + n0 + tid];

  int wave = tid >> 6, lane = tid & 63;
  int lr = lane & 15, koff = (lane >> 4) * 8;
  const __bf16* qb = qr + ((size_t)(bz * NL + m0 + lr)) * DHEAD + koff;
  bf16x8 a0 = *(const bf16x8*)qb;
  bf16x8 a1 = *(const bf16x8*)(qb + 32);
  int rowb = (lane >> 4) * 4;
  #pragma unroll
  for (int s = 0; s < 2; ++s) {
    int ncol = (wave * 2 + s) * 16;
    const __bf16* kb = kr + ((size_t)(bz * NL + n0 + ncol + lr)) * DHEAD + koff;
    bf16x8 b0f = *(const bf16x8*)kb;
    bf16x8 b1f = *(const bf16x8*)(kb + 32);
    f32x4 acc = {0,0,0,0};
    acc = __builtin_amdgcn_mfma_f32_16x16x32_bf16(a0, b0f, acc, 0, 0, 0);
    acc = __builtin_amdgcn_mfma_f32_16x16x32_bf16(a1, b1f, acc, 0, 0, 0);
    #pragma unroll
    for (int r = 0; r < 4; ++r) ls[rowb + r][ncol + lr] = acc[r] * 0.125f;
  }
  __syncthreads();

  #pragma unroll
  for (int half = 0; half < 2; ++half) {
    int flat = half * 1024 + tid * 4;
    int rr = flat >> 7, c = flat & 127;
    int mg = m0 + rr;
    f32x4 s4 = *(f32x4*)&ls[rr][c];
    f32x4 pv = *(f32x4*)&padf[c];
    f32x4 sm;
    #pragma unroll
    for (int j = 0; j < 4; ++j) {
      float v = s4[j] * pv[j] - (1.f - pv[j]) * BIGNEG;
      if (mg > n0 + c + j) v -= BIGNEG;
      sm[j] = v;
    }
    float* ob = out + ((size_t)(bz * NHEADS) * NL + mg) * NL + n0 + c;
    #pragma unroll
    for (int h = 0; h < NHEADS; ++h) {
      f32x4 b1v = *(f32x4*)&b1h[h][c];
      float b0v = b0h[h][rr];
      f32x4 o;
      #pragma unroll
      for (int j = 0; j < 4; ++j)
        o[j] = sm[j] + (b0v + b1v[j]) * pv[j];
      __builtin_nontemporal_store(o, (f32x4*)(ob + (size_t)h * NL * NL));
    }
  }
}

extern "C" void kernel_launch(void* const* d_in, const int* in_sizes, int n_in,
                              void* d_out, int out_size, void* d_ws, size_t ws_size,
                              hipStream_t stream) {
  const float* hidden = (const float*)d_in[0];
  const int*   amask  = (const int*)d_in[1];
  const float* pW     = (const float*)d_in[2];
  const float* pb     = (const float*)d_in[3];
  const float* qW     = (const float*)d_in[4];
  const float* qb     = (const float*)d_in[5];
  float* out = (float*)d_out;
  char*  ws  = (char*)d_ws;
  __bf16* pWT  = (__bf16*)(ws + OFF_PWT);
  float*  b2   = (float*)(ws + OFF_B2);
  __bf16* qrB  = (__bf16*)(ws + OFF_QRB);
  __bf16* krB  = (__bf16*)(ws + OFF_KRB);
  float*  bias = (float*)(ws + OFF_BIAS);

  prep_wt<<<577, 256, 0, stream>>>(pW, qW, pb, qb, pWT, b2);
  // gemm_rope launched TWICE on purpose (idempotent: pure function of
  // hidden/pWT -> qrB/krB/biasw). dur_us - 81.2 baseline arithmetic gives
  // T_gemm attribution that the fill-flooded rocprof top-5 cannot.
  gemm_rope<<<NROWS / 16, 256, 0, stream>>>(hidden, pWT, pb, b2, qrB, krB, bias);
  gemm_rope<<<NROWS / 16, 256, 0, stream>>>(hidden, pWT, pb, b2, qrB, krB, bias);
  logits_kernel<<<dim3(4, NL / 16, NB), 256, 0, stream>>>(qrB, krB, bias, amask, out);
}

// Round 7
// 58.247 us; speedup vs baseline: 2.0756x; 1.7343x over previous
//
#include <hip/hip_runtime.h>
#include <hip/hip_bf16.h>
#include <cstddef>

typedef __bf16 bf16x8 __attribute__((ext_vector_type(8)));
typedef float  f32x4  __attribute__((ext_vector_type(4)));

#define NB 16
#define NL 512
#define NH 768
#define NROWS (NB*NL)      // 8192
#define NSEQ 128           // seq columns
#define NPAD 192           // padded GEMM N: 128 seq + 24 bias + 40 zero
#define NHEADS 12
#define NBIAS 24           // 2*HEADS
#define DHEAD 64
#define BIGNEG 1000000000000.0f

// workspace byte offsets
#define OFF_PWT   0            // bf16 k-panel [96][192][8] = 294912 B
#define OFF_B2    294912       // f32 [24] (pad 128)
#define OFF_QRB   295040       // bf16 [16][512][64] = 1 MB  (roped q, [l][d])
#define OFF_KRB   1343616      // bf16 [16][512][64] = 1 MB
#define OFF_BIAS  2392192      // f32 [16][2][12][512] = 786432 B (b0/b1 planes)
// total 3178624 B

// pWT k-panel layout: element (n,k) at [(k>>3)*192 + n]*8 + (k&7).
__global__ void prep_wt(const float* __restrict__ pW, const float* __restrict__ qW,
                        const float* __restrict__ pb, const float* __restrict__ qb,
                        __bf16* __restrict__ pWT, float* __restrict__ b2) {
  if (blockIdx.x == 576) {
    int c = threadIdx.x;
    if (c < NBIAS) {
      float a = qb[c];
      for (int j = 0; j < NSEQ; ++j) a += pb[j] * qW[j * NBIAS + c];
      b2[c] = a;
    }
    return;
  }
  int idx = blockIdx.x * 256 + threadIdx.x;   // covers NPAD*NH exactly
  int n = idx / NH, k = idx % NH;
  float v = 0.f;
  if (n < NSEQ) {
    v = pW[k * NSEQ + n];
  } else if (n < NSEQ + NBIAS) {
    int c = n - NSEQ;
    float a = 0.f;
    for (int j = 0; j < NSEQ; ++j) a += pW[k * NSEQ + j] * qW[j * NBIAS + c];
    v = a;
  }
  pWT[((size_t)(k >> 3) * NPAD + n) * 8 + (k & 7)] = (__bf16)v;
}

// GEMM + RoPE. A staged via LDS: global loads are 2-rows-x-512B coalesced
// (~24 transactions/wave vs ~2000 for the old row-strided direct frags).
__launch_bounds__(256)
__global__ void gemm_rope(const float* __restrict__ hidden, const __bf16* __restrict__ pWT,
                          const float* __restrict__ pb, const float* __restrict__ b2,
                          __bf16* __restrict__ qrB, __bf16* __restrict__ krB,
                          float* __restrict__ biasw) {
  int m0 = blockIdx.x * 16;
  int tid = threadIdx.x;
  int wave = tid >> 6, lane = tid & 63;
  int lrow = lane & 15, lkg = lane >> 4, lk = lkg * 8;
  __shared__ float as[16][132];               // row stride 528B = 33*16B (aligned)
  f32x4 acc0 = {0,0,0,0}, acc1 = {0,0,0,0}, acc2 = {0,0,0,0};
  const __bf16* bb0 = pWT + (size_t)lkg * NPAD * 8 + ((wave*3+0)*16 + lrow) * 8;
  const __bf16* bb1 = pWT + (size_t)lkg * NPAD * 8 + ((wave*3+1)*16 + lrow) * 8;
  const __bf16* bb2 = pWT + (size_t)lkg * NPAD * 8 + ((wave*3+2)*16 + lrow) * 8;
  // staging map: thread -> (row, 8 cols); wave-instr = 4 rows x 512B segments
  int srow = tid >> 4, scol = (tid & 15) * 8;
  const float* gsrc = hidden + (size_t)(m0 + srow) * NH + scol;
  f32x4 v0 = *(const f32x4*)(gsrc);
  f32x4 v1 = *(const f32x4*)(gsrc + 4);
  for (int ch = 0; ch < 6; ++ch) {
    __syncthreads();                          // prev chunk's reads done
    *(f32x4*)&as[srow][scol]     = v0;
    *(f32x4*)&as[srow][scol + 4] = v1;
    __syncthreads();
    if (ch < 5) {                             // prefetch next chunk under compute
      v0 = *(const f32x4*)(gsrc + (ch + 1) * 128);
      v1 = *(const f32x4*)(gsrc + (ch + 1) * 128 + 4);
    }
    #pragma unroll
    for (int kk = 0; kk < 4; ++kk) {
      int kloc = kk * 32 + lk;
      f32x4 a0 = *(f32x4*)&as[lrow][kloc];
      f32x4 a1 = *(f32x4*)&as[lrow][kloc + 4];
      bf16x8 af;
      af[0]=(__bf16)a0[0]; af[1]=(__bf16)a0[1]; af[2]=(__bf16)a0[2]; af[3]=(__bf16)a0[3];
      af[4]=(__bf16)a1[0]; af[5]=(__bf16)a1[1]; af[6]=(__bf16)a1[2]; af[7]=(__bf16)a1[3];
      size_t kglob = (size_t)(ch * 128 + kk * 32) * NPAD;
      bf16x8 b0 = *(const bf16x8*)(bb0 + kglob);
      bf16x8 b1 = *(const bf16x8*)(bb1 + kglob);
      bf16x8 b2f = *(const bf16x8*)(bb2 + kglob);
      acc0 = __builtin_amdgcn_mfma_f32_16x16x32_bf16(af, b0, acc0, 0, 0, 0);
      acc1 = __builtin_amdgcn_mfma_f32_16x16x32_bf16(af, b1, acc1, 0, 0, 0);
      acc2 = __builtin_amdgcn_mfma_f32_16x16x32_bf16(af, b2f, acc2, 0, 0, 0);
    }
  }
  int rowoff = lkg * 4;
  #pragma unroll
  for (int f = 0; f < 3; ++f) {
    f32x4 a = (f == 0) ? acc0 : (f == 1) ? acc1 : acc2;
    int col = (wave*3 + f) * 16 + lrow;
    bool isseq = (col < NSEQ);
    float addc = isseq ? pb[col] : ((col < NSEQ + NBIAS) ? b2[col - NSEQ] : 0.f);
    #pragma unroll
    for (int r = 0; r < 4; ++r) {
      int rg = m0 + rowoff + r;
      float val = a[r] + addc;
      if (isseq) {
        float pv = __shfl_xor(val, 1, 64);
        int d = col & 63;
        float x2 = (d & 1) ? pv : -pv;
        int p = d >> 1;
        float ang = (float)(rg & (NL - 1)) * __expf((float)p * (-9.210340371976184f / 32.0f));
        float sn = __sinf(ang), cs = __cosf(ang);
        float res = val * cs + x2 * sn;
        int bi = rg >> 9, l = rg & (NL - 1);
        __bf16* dst = (col < DHEAD) ? qrB : krB;
        dst[((size_t)bi * NL + l) * DHEAD + d] = (__bf16)res;
      } else if (col < NSEQ + NBIAS) {
        int c2 = col - NSEQ;
        int h = c2 >> 1, par = c2 & 1;
        int bi = rg >> 9, l = rg & (NL - 1);
        biasw[(((size_t)bi * 2 + par) * NHEADS + h) * NL + l] = val;
      }
    }
  }
}

__launch_bounds__(256)
__global__ void logits_kernel(const __bf16* __restrict__ qr, const __bf16* __restrict__ kr,
                              const float* __restrict__ biasw, const int* __restrict__ amask,
                              float* __restrict__ out) {
  int nx = blockIdx.x, mt = blockIdx.y, bz = blockIdx.z;
  int n0 = nx * 128, m0 = mt * 16;
  int tid = threadIdx.x;
  __shared__ float ls[16][128];
  __shared__ float b1h[NHEADS][128];
  __shared__ float b0h[NHEADS][16];
  __shared__ float padf[128];
  const float* bw = biasw + (size_t)bz * 2 * NHEADS * NL;
  for (int i = tid; i < NHEADS * 128 / 4; i += 256) {
    int h = i >> 5, c = (i & 31) * 4;
    *(f32x4*)&b1h[h][c] = *(const f32x4*)(bw + NHEADS * NL + h * NL + n0 + c);
  }
  if (tid < NHEADS * 16) {
    int h = tid >> 4, r = tid & 15;
    b0h[h][r] = bw[h * NL + m0 + r];
  }
  if (tid < 128) padf[tid] = (float)amask[bz * NL + n0 + tid];

  int wave = tid >> 6, lane = tid & 63;
  int lr = lane & 15, koff = (lane >> 4) * 8;
  const __bf16* qb = qr + ((size_t)(bz * NL + m0 + lr)) * DHEAD + koff;
  bf16x8 a0 = *(const bf16x8*)qb;
  bf16x8 a1 = *(const bf16x8*)(qb + 32);
  int rowb = (lane >> 4) * 4;
  #pragma unroll
  for (int s = 0; s < 2; ++s) {
    int ncol = (wave * 2 + s) * 16;
    const __bf16* kb = kr + ((size_t)(bz * NL + n0 + ncol + lr)) * DHEAD + koff;
    bf16x8 b0f = *(const bf16x8*)kb;
    bf16x8 b1f = *(const bf16x8*)(kb + 32);
    f32x4 acc = {0,0,0,0};
    acc = __builtin_amdgcn_mfma_f32_16x16x32_bf16(a0, b0f, acc, 0, 0, 0);
    acc = __builtin_amdgcn_mfma_f32_16x16x32_bf16(a1, b1f, acc, 0, 0, 0);
    #pragma unroll
    for (int r = 0; r < 4; ++r) ls[rowb + r][ncol + lr] = acc[r] * 0.125f;
  }
  __syncthreads();

  #pragma unroll
  for (int half = 0; half < 2; ++half) {
    int flat = half * 1024 + tid * 4;
    int rr = flat >> 7, c = flat & 127;
    int mg = m0 + rr;
    f32x4 s4 = *(f32x4*)&ls[rr][c];
    f32x4 pv = *(f32x4*)&padf[c];
    f32x4 sm;
    #pragma unroll
    for (int j = 0; j < 4; ++j) {
      float v = s4[j] * pv[j] - (1.f - pv[j]) * BIGNEG;
      if (mg > n0 + c + j) v -= BIGNEG;
      sm[j] = v;
    }
    float* ob = out + ((size_t)(bz * NHEADS) * NL + mg) * NL + n0 + c;
    #pragma unroll
    for (int h = 0; h < NHEADS; ++h) {
      f32x4 b1v = *(f32x4*)&b1h[h][c];
      float b0v = b0h[h][rr];
      f32x4 o;
      #pragma unroll
      for (int j = 0; j < 4; ++j)
        o[j] = sm[j] + (b0v + b1v[j]) * pv[j];
      *(f32x4*)(ob + (size_t)h * NL * NL) = o;   // normal store (vs NT): test
    }
  }
}

extern "C" void kernel_launch(void* const* d_in, const int* in_sizes, int n_in,
                              void* d_out, int out_size, void* d_ws, size_t ws_size,
                              hipStream_t stream) {
  const float* hidden = (const float*)d_in[0];
  const int*   amask  = (const int*)d_in[1];
  const float* pW     = (const float*)d_in[2];
  const float* pb     = (const float*)d_in[3];
  const float* qW     = (const float*)d_in[4];
  const float* qb     = (const float*)d_in[5];
  float* out = (float*)d_out;
  char*  ws  = (char*)d_ws;
  __bf16* pWT  = (__bf16*)(ws + OFF_PWT);
  float*  b2   = (float*)(ws + OFF_B2);
  __bf16* qrB  = (__bf16*)(ws + OFF_QRB);
  __bf16* krB  = (__bf16*)(ws + OFF_KRB);
  float*  bias = (float*)(ws + OFF_BIAS);

  prep_wt<<<577, 256, 0, stream>>>(pW, qW, pb, qb, pWT, b2);
  gemm_rope<<<NROWS / 16, 256, 0, stream>>>(hidden, pWT, pb, b2, qrB, krB, bias);
  logits_kernel<<<dim3(4, NL / 16, NB), 256, 0, stream>>>(qrB, krB, bias, amask, out);
}